// Round 4
// baseline (691.367 us; speedup 1.0000x reference)
//
#include <hip/hip_runtime.h>
#include <hip/hip_bf16.h>
#include <math.h>

// Problem constants (B,T,S,DQ,DKV,DOUT fixed by the reference)
#define B_SZ 2
#define T_SZ 1024
#define S_SZ 1024
#define NQ 16
#define NKV 4
#define HD 128
#define DQ 2048
#define DKV 2048
#define DOUT 2048

typedef __bf16 bf16x8 __attribute__((ext_vector_type(8)));
typedef float f32x4 __attribute__((ext_vector_type(4)));

// ---- dtype-generic 8-element load -> bf16x8 (fp32 inputs converted) -------
__device__ inline bf16x8 load8_bf16(const float* p) {
    float4 a = *reinterpret_cast<const float4*>(p);
    float4 b = *reinterpret_cast<const float4*>(p + 4);
    bf16x8 r;
    r[0] = (__bf16)a.x; r[1] = (__bf16)a.y; r[2] = (__bf16)a.z; r[3] = (__bf16)a.w;
    r[4] = (__bf16)b.x; r[5] = (__bf16)b.y; r[6] = (__bf16)b.z; r[7] = (__bf16)b.w;
    return r;
}
__device__ inline bf16x8 load8_bf16(const __bf16* p) {
    return *reinterpret_cast<const bf16x8*>(p);
}
// ---- split fp32 -> hi/lo bf16 (x ~= hi + lo, rel err ~2^-17) --------------
__device__ inline void split8(const float* p, bf16x8& hi, bf16x8& lo) {
    float4 a = *reinterpret_cast<const float4*>(p);
    float4 b = *reinterpret_cast<const float4*>(p + 4);
    float v[8] = {a.x, a.y, a.z, a.w, b.x, b.y, b.z, b.w};
    #pragma unroll
    for (int i = 0; i < 8; ++i) {
        __bf16 h = (__bf16)v[i];
        hi[i] = h;
        lo[i] = (__bf16)(v[i] - (float)h);
    }
}

// ---------------------------------------------------------------------------
// Generic NN GEMM (plain bf16 path): C[M,N] = A[M,K]*B[K,N]; fp32 acc.
// Block = 256 thr (4 waves), tile 64x64, K-step 32.
// Verified fragment maps (learn_hip m89/m91/m120):
//   A-frag: lane holds A[m=lane&15][k=quad*8+j]
//   B-frag: lane holds B[k=quad*8+j][n=lane&15]  (B stored transposed in LDS)
//   C/D:    D[row=quad*4+r][col=lane&15]
// ---------------------------------------------------------------------------
template <typename TA, typename TB, typename TC>
__global__ __launch_bounds__(256) void gemm_nn(const TA* __restrict__ A,
                                               const TB* __restrict__ B,
                                               TC* __restrict__ C,
                                               int M, int N, int K) {
    __shared__ __align__(16) __bf16 As[64][32];
    __shared__ __align__(16) __bf16 Bs[64][32];
    const int tid = threadIdx.x;
    const int lane = tid & 63, w = tid >> 6;
    const int quad = lane >> 4, l16 = lane & 15;
    const int bm = blockIdx.y * 64, bn = blockIdx.x * 64;
    const int wm = (w >> 1) * 32, wn = (w & 1) * 32;

    f32x4 acc[2][2];
    #pragma unroll
    for (int i = 0; i < 2; ++i)
        #pragma unroll
        for (int j = 0; j < 2; ++j)
            acc[i][j] = (f32x4){0.f, 0.f, 0.f, 0.f};

    const int ar = tid >> 2, akc = (tid & 3) * 8;
    const int bkk = tid >> 3, bc8 = (tid & 7) * 8;

    for (int k0 = 0; k0 < K; k0 += 32) {
        __syncthreads();
        *reinterpret_cast<bf16x8*>(&As[ar][akc]) =
            load8_bf16(&A[(size_t)(bm + ar) * K + k0 + akc]);
        bf16x8 bv = load8_bf16(&B[(size_t)(k0 + bkk) * N + bn + bc8]);
        #pragma unroll
        for (int j = 0; j < 8; ++j) Bs[bc8 + j][bkk] = bv[j];
        __syncthreads();

        bf16x8 af0 = *reinterpret_cast<const bf16x8*>(&As[wm + l16][quad * 8]);
        bf16x8 af1 = *reinterpret_cast<const bf16x8*>(&As[wm + 16 + l16][quad * 8]);
        bf16x8 bf0 = *reinterpret_cast<const bf16x8*>(&Bs[wn + l16][quad * 8]);
        bf16x8 bf1 = *reinterpret_cast<const bf16x8*>(&Bs[wn + 16 + l16][quad * 8]);
        acc[0][0] = __builtin_amdgcn_mfma_f32_16x16x32_bf16(af0, bf0, acc[0][0], 0, 0, 0);
        acc[0][1] = __builtin_amdgcn_mfma_f32_16x16x32_bf16(af0, bf1, acc[0][1], 0, 0, 0);
        acc[1][0] = __builtin_amdgcn_mfma_f32_16x16x32_bf16(af1, bf0, acc[1][0], 0, 0, 0);
        acc[1][1] = __builtin_amdgcn_mfma_f32_16x16x32_bf16(af1, bf1, acc[1][1], 0, 0, 0);
    }

    #pragma unroll
    for (int mi = 0; mi < 2; ++mi)
        #pragma unroll
        for (int ni = 0; ni < 2; ++ni)
            #pragma unroll
            for (int r = 0; r < 4; ++r)
                C[(size_t)(bm + wm + 16 * mi + quad * 4 + r) * N + bn + wn + 16 * ni + l16] =
                    (TC)acc[mi][ni][r];
}

// ---------------------------------------------------------------------------
// Split-bf16 GEMM (fp32-grade): C = A*B with A,B fp32 split into hi+lo bf16;
// acc += Ah*Bh + Ah*Bl + Al*Bh  (lo*lo dropped, rel err ~2^-17). C fp32.
// Used for Q and K projections (the precision-critical score path).
// ---------------------------------------------------------------------------
__global__ __launch_bounds__(256) void gemm_nn_split(const float* __restrict__ A,
                                                     const float* __restrict__ B,
                                                     float* __restrict__ C,
                                                     int M, int N, int K) {
    __shared__ __align__(16) __bf16 Ah[64][32], Al[64][32];
    __shared__ __align__(16) __bf16 Bh[64][32], Bl[64][32];
    const int tid = threadIdx.x;
    const int lane = tid & 63, w = tid >> 6;
    const int quad = lane >> 4, l16 = lane & 15;
    const int bm = blockIdx.y * 64, bn = blockIdx.x * 64;
    const int wm = (w >> 1) * 32, wn = (w & 1) * 32;

    f32x4 acc[2][2];
    #pragma unroll
    for (int i = 0; i < 2; ++i)
        #pragma unroll
        for (int j = 0; j < 2; ++j)
            acc[i][j] = (f32x4){0.f, 0.f, 0.f, 0.f};

    const int ar = tid >> 2, akc = (tid & 3) * 8;
    const int bkk = tid >> 3, bc8 = (tid & 7) * 8;

    for (int k0 = 0; k0 < K; k0 += 32) {
        __syncthreads();
        bf16x8 h, l;
        split8(&A[(size_t)(bm + ar) * K + k0 + akc], h, l);
        *reinterpret_cast<bf16x8*>(&Ah[ar][akc]) = h;
        *reinterpret_cast<bf16x8*>(&Al[ar][akc]) = l;
        split8(&B[(size_t)(k0 + bkk) * N + bn + bc8], h, l);
        #pragma unroll
        for (int j = 0; j < 8; ++j) { Bh[bc8 + j][bkk] = h[j]; Bl[bc8 + j][bkk] = l[j]; }
        __syncthreads();

        bf16x8 ah[2], al[2], bh[2], bl[2];
        #pragma unroll
        for (int i = 0; i < 2; ++i) {
            ah[i] = *reinterpret_cast<const bf16x8*>(&Ah[wm + 16 * i + l16][quad * 8]);
            al[i] = *reinterpret_cast<const bf16x8*>(&Al[wm + 16 * i + l16][quad * 8]);
            bh[i] = *reinterpret_cast<const bf16x8*>(&Bh[wn + 16 * i + l16][quad * 8]);
            bl[i] = *reinterpret_cast<const bf16x8*>(&Bl[wn + 16 * i + l16][quad * 8]);
        }
        #pragma unroll
        for (int mi = 0; mi < 2; ++mi)
            #pragma unroll
            for (int ni = 0; ni < 2; ++ni) {
                acc[mi][ni] = __builtin_amdgcn_mfma_f32_16x16x32_bf16(ah[mi], bh[ni], acc[mi][ni], 0, 0, 0);
                acc[mi][ni] = __builtin_amdgcn_mfma_f32_16x16x32_bf16(ah[mi], bl[ni], acc[mi][ni], 0, 0, 0);
                acc[mi][ni] = __builtin_amdgcn_mfma_f32_16x16x32_bf16(al[mi], bh[ni], acc[mi][ni], 0, 0, 0);
            }
    }

    #pragma unroll
    for (int mi = 0; mi < 2; ++mi)
        #pragma unroll
        for (int ni = 0; ni < 2; ++ni)
            #pragma unroll
            for (int r = 0; r < 4; ++r)
                C[(size_t)(bm + wm + 16 * mi + quad * 4 + r) * N + bn + wn + 16 * ni + l16] =
                    acc[mi][ni][r];
}

// ---------------------------------------------------------------------------
// RoPE in-place on fp32 x:(B,L,N,HD). half=64. ts = 10000^(h/64).
// ---------------------------------------------------------------------------
__global__ __launch_bounds__(256) void rope_kernel(float* __restrict__ x,
                                                   const int* __restrict__ pos,
                                                   int N) {
    size_t idx = (size_t)blockIdx.x * 256 + threadIdx.x;
    int h = (int)(idx & 63);
    size_t g = idx >> 6;            // (b*L + l)*N + n
    size_t bl = g / (size_t)N;      // b*L + l
    float p = (float)pos[bl];
    float ts = powf(10000.f, (float)h * (1.f / 64.f));
    float ang = p / ts;
    float s = sinf(ang), c = cosf(ang);
    size_t base = g * HD;
    float x1 = x[base + h];
    float x2 = x[base + h + 64];
    x[base + h]      = x1 * c - x2 * s;
    x[base + h + 64] = x2 * c + x1 * s;
}

// ---------------------------------------------------------------------------
// Flash attention (non-causal, scale=1.0, GQA group=4), split-precision QK^T.
// Q,K fp32 (RoPE applied); V bf16; O bf16.
// Block = 256 thr (4 waves); block owns 64 q-rows of one (b, q-head).
// Q fragments (hi/lo) live in registers; K staged hi/lo in LDS.
// P converts C-layout -> A-layout via per-wave LDS round-trip (m120 pattern).
// LDS: Ksh 16K + Ksl 16K + Vt 18K + Ps 4K = 54 KB.
// ---------------------------------------------------------------------------
__global__ __launch_bounds__(256) void attn_kernel(const float* __restrict__ Q,
                                                   const float* __restrict__ K,
                                                   const __bf16* __restrict__ V,
                                                   __bf16* __restrict__ O) {
    __shared__ __align__(16) __bf16 Ksh[64][128], Ksl[64][128];
    __shared__ __align__(16) __bf16 Vt[128][72];
    __shared__ __align__(16) __bf16 Ps[4][16][32];
    const int tid = threadIdx.x, lane = tid & 63, w = tid >> 6;
    const int quad = lane >> 4, l16 = lane & 15;
    const int blk = blockIdx.x;
    const int t0 = (blk & 15) * 64;       // T/64 = 16 q-tiles
    const int n  = (blk >> 4) & 15;       // q head
    const int b  = blk >> 8;              // batch
    const int kn = n >> 2;                // kv head (G=4)

    // Q fragments for this wave's 16 rows, split hi/lo, in registers.
    // A-frag: lane holds Q[row=w*16+l16][k=kh*32+quad*8+j]
    bf16x8 qh[4], ql[4];
    #pragma unroll
    for (int kh = 0; kh < 4; ++kh) {
        const float* qp = &Q[(((size_t)b * T_SZ + t0 + w * 16 + l16) * NQ + n) * HD + kh * 32 + quad * 8];
        split8(qp, qh[kh], ql[kh]);
    }

    f32x4 o_acc[8];
    #pragma unroll
    for (int i = 0; i < 8; ++i) o_acc[i] = (f32x4){0.f, 0.f, 0.f, 0.f};
    float m_row[4] = {-1e30f, -1e30f, -1e30f, -1e30f};
    float l_row[4] = {0.f, 0.f, 0.f, 0.f};

    for (int s0 = 0; s0 < S_SZ; s0 += 64) {
        __syncthreads();
        #pragma unroll
        for (int i = 0; i < 4; ++i) {
            int e = tid + i * 256;
            int r = e >> 4, c = (e & 15) * 8;
            bf16x8 h, l;
            split8(&K[(((size_t)b * S_SZ + s0 + r) * NKV + kn) * HD + c], h, l);
            *reinterpret_cast<bf16x8*>(&Ksh[r][c]) = h;
            *reinterpret_cast<bf16x8*>(&Ksl[r][c]) = l;
            bf16x8 vv = *reinterpret_cast<const bf16x8*>(
                &V[(((size_t)b * S_SZ + s0 + r) * NKV + kn) * HD + c]);
            #pragma unroll
            for (int j = 0; j < 8; ++j) Vt[c + j][r] = vv[j];
        }
        __syncthreads();

        #pragma unroll
        for (int sc = 0; sc < 2; ++sc) {
            // ---- scores: split QK^T (hi*hi + hi*lo + lo*hi) ----
            f32x4 sf[2];
            #pragma unroll
            for (int j2 = 0; j2 < 2; ++j2) {
                f32x4 sa = (f32x4){0.f, 0.f, 0.f, 0.f};
                #pragma unroll
                for (int kh = 0; kh < 4; ++kh) {
                    const int kr = sc * 32 + j2 * 16 + l16, kc = kh * 32 + quad * 8;
                    bf16x8 bkh = *reinterpret_cast<const bf16x8*>(&Ksh[kr][kc]);
                    bf16x8 bkl = *reinterpret_cast<const bf16x8*>(&Ksl[kr][kc]);
                    sa = __builtin_amdgcn_mfma_f32_16x16x32_bf16(qh[kh], bkh, sa, 0, 0, 0);
                    sa = __builtin_amdgcn_mfma_f32_16x16x32_bf16(qh[kh], bkl, sa, 0, 0, 0);
                    sa = __builtin_amdgcn_mfma_f32_16x16x32_bf16(ql[kh], bkh, sa, 0, 0, 0);
                }
                sf[j2] = sa;
            }
            // ---- online softmax (row = quad*4+r, reduce across 16 lanes) ----
            float alpha[4];
            #pragma unroll
            for (int r = 0; r < 4; ++r) {
                float mc = fmaxf(sf[0][r], sf[1][r]);
                #pragma unroll
                for (int off = 1; off < 16; off <<= 1)
                    mc = fmaxf(mc, __shfl_xor(mc, off, 64));
                float mn = fmaxf(m_row[r], mc);
                alpha[r] = fminf(expf(m_row[r] - mn), 1.f);
                m_row[r] = mn;
                float p0 = fminf(expf(sf[0][r] - mn), 1.f);
                float p1 = fminf(expf(sf[1][r] - mn), 1.f);
                sf[0][r] = p0; sf[1][r] = p1;
                float rs = p0 + p1;
                #pragma unroll
                for (int off = 1; off < 16; off <<= 1)
                    rs += __shfl_xor(rs, off, 64);
                l_row[r] = l_row[r] * alpha[r] + rs;
            }
            #pragma unroll
            for (int ht = 0; ht < 8; ++ht)
                #pragma unroll
                for (int r = 0; r < 4; ++r)
                    o_acc[ht][r] *= alpha[r];
            // ---- P: C-layout -> A-layout via per-wave LDS slice ----
            #pragma unroll
            for (int r = 0; r < 4; ++r) {
                Ps[w][quad * 4 + r][l16]      = (__bf16)sf[0][r];
                Ps[w][quad * 4 + r][16 + l16] = (__bf16)sf[1][r];
            }
            __syncthreads();
            bf16x8 ap = *reinterpret_cast<const bf16x8*>(&Ps[w][l16][quad * 8]);
            __syncthreads();
            // ---- O += P @ V ----
            #pragma unroll
            for (int ht = 0; ht < 8; ++ht) {
                bf16x8 bv = *reinterpret_cast<const bf16x8*>(&Vt[ht * 16 + l16][sc * 32 + quad * 8]);
                o_acc[ht] = __builtin_amdgcn_mfma_f32_16x16x32_bf16(ap, bv, o_acc[ht], 0, 0, 0);
            }
        }
    }

    float inv_l[4];
    #pragma unroll
    for (int r = 0; r < 4; ++r) inv_l[r] = 1.f / fmaxf(l_row[r], 1e-30f);
    #pragma unroll
    for (int ht = 0; ht < 8; ++ht)
        #pragma unroll
        for (int r = 0; r < 4; ++r)
            O[(((size_t)b * T_SZ + t0 + w * 16 + quad * 4 + r) * NQ + n) * HD + ht * 16 + l16] =
                (__bf16)(o_acc[ht][r] * inv_l[r]);
}

// ---------------------------------------------------------------------------
extern "C" void kernel_launch(void* const* d_in, const int* in_sizes, int n_in,
                              void* d_out, int out_size, void* d_ws, size_t ws_size,
                              hipStream_t stream) {
    const float* Xq   = (const float*)d_in[0];   // (B,T,DQ)
    const float* Xkv  = (const float*)d_in[1];   // (B,S,DKV)
    const int*   qpos = (const int*)d_in[2];     // (B,T)
    const int*   kpos = (const int*)d_in[3];     // (B,S)
    const float* Wq   = (const float*)d_in[4];   // (DQ, NQ*HD)
    const float* Wk   = (const float*)d_in[5];   // (DKV, NKV*HD)
    const float* Wv   = (const float*)d_in[6];   // (DKV, NKV*HD)
    const float* Wo   = (const float*)d_in[7];   // (NQ*HD, DOUT)
    float* out = (float*)d_out;                  // (B,T,DOUT) fp32

    // workspace: Qf 16.8MB fp32 | Kf 4.2MB fp32 | Vb 2.1MB bf16 | Ab 8.4MB bf16
    float* Qf = (float*)d_ws;
    float* Kf = Qf + (size_t)B_SZ * T_SZ * NQ * HD;
    __bf16* Vb = (__bf16*)(Kf + (size_t)B_SZ * S_SZ * NKV * HD);
    __bf16* Ab = Vb + (size_t)B_SZ * S_SZ * NKV * HD;

    dim3 blk(256);
    // Q,K projections: split-precision (score path) -> fp32 workspace
    gemm_nn_split<<<dim3((NQ * HD) / 64, (B_SZ * T_SZ) / 64), blk, 0, stream>>>(
        Xq, Wq, Qf, B_SZ * T_SZ, NQ * HD, DQ);
    gemm_nn_split<<<dim3((NKV * HD) / 64, (B_SZ * S_SZ) / 64), blk, 0, stream>>>(
        Xkv, Wk, Kf, B_SZ * S_SZ, NKV * HD, DKV);
    // V projection: plain bf16 path
    gemm_nn<float, float, __bf16><<<dim3((NKV * HD) / 64, (B_SZ * S_SZ) / 64), blk, 0, stream>>>(
        Xkv, Wv, Vb, B_SZ * S_SZ, NKV * HD, DKV);
    // RoPE on q and k (fp32)
    rope_kernel<<<(B_SZ * T_SZ * NQ * 64) / 256, blk, 0, stream>>>(Qf, qpos, NQ);
    rope_kernel<<<(B_SZ * S_SZ * NKV * 64) / 256, blk, 0, stream>>>(Kf, kpos, NKV);
    // GQA flash attention (split QK^T) -> attn bf16 (B,T,NQ,HD)
    attn_kernel<<<B_SZ * NQ * (T_SZ / 64), blk, 0, stream>>>(Qf, Kf, Vb, Ab);
    // output projection: bf16 attn x fp32 Wo -> fp32 out
    gemm_nn<__bf16, float, float><<<dim3(DOUT / 64, (B_SZ * T_SZ) / 64), blk, 0, stream>>>(
        Ab, Wo, out, B_SZ * T_SZ, DOUT, NQ * HD);
}

// Round 5
// 515.412 us; speedup vs baseline: 1.3414x; 1.3414x over previous
//
#include <hip/hip_runtime.h>
#include <hip/hip_bf16.h>
#include <math.h>

// Problem constants (B,T,S,DQ,DKV,DOUT fixed by the reference)
#define B_SZ 2
#define T_SZ 1024
#define S_SZ 1024
#define NQ 16
#define NKV 4
#define HD 128
#define DQ 2048
#define DKV 2048
#define DOUT 2048

typedef __bf16 bf16x8 __attribute__((ext_vector_type(8)));
typedef float f32x4 __attribute__((ext_vector_type(4)));

// ---- dtype-generic 8-element load -> bf16x8 (fp32 inputs converted) -------
__device__ inline bf16x8 load8_bf16(const float* p) {
    float4 a = *reinterpret_cast<const float4*>(p);
    float4 b = *reinterpret_cast<const float4*>(p + 4);
    bf16x8 r;
    r[0] = (__bf16)a.x; r[1] = (__bf16)a.y; r[2] = (__bf16)a.z; r[3] = (__bf16)a.w;
    r[4] = (__bf16)b.x; r[5] = (__bf16)b.y; r[6] = (__bf16)b.z; r[7] = (__bf16)b.w;
    return r;
}
__device__ inline bf16x8 load8_bf16(const __bf16* p) {
    return *reinterpret_cast<const bf16x8*>(p);
}
// ---- split fp32 -> hi/lo bf16 (x ~= hi + lo, rel err ~2^-17) --------------
__device__ inline void split8(const float* p, bf16x8& hi, bf16x8& lo) {
    float4 a = *reinterpret_cast<const float4*>(p);
    float4 b = *reinterpret_cast<const float4*>(p + 4);
    float v[8] = {a.x, a.y, a.z, a.w, b.x, b.y, b.z, b.w};
    #pragma unroll
    for (int i = 0; i < 8; ++i) {
        __bf16 h = (__bf16)v[i];
        hi[i] = h;
        lo[i] = (__bf16)(v[i] - (float)h);
    }
}

// ---------------------------------------------------------------------------
// Generic NN GEMM (plain bf16 path): C[M,N] = A[M,K]*B[K,N]; fp32 acc.
// Block = 256 thr (4 waves), tile 64x64, K-step 32.
// B staged k-major per lane: writes to Bs[n][k] hit 16 banks (4-way, 1.58x)
// instead of the old n-major mapping's 4 banks (16-way, 5.7x).
// ---------------------------------------------------------------------------
template <typename TA, typename TB, typename TC>
__global__ __launch_bounds__(256) void gemm_nn(const TA* __restrict__ A,
                                               const TB* __restrict__ B,
                                               TC* __restrict__ C,
                                               int M, int N, int K) {
    __shared__ __align__(16) __bf16 As[64][32];
    __shared__ __align__(16) __bf16 Bs[64][32];
    const int tid = threadIdx.x;
    const int lane = tid & 63, w = tid >> 6;
    const int quad = lane >> 4, l16 = lane & 15;
    const int bm = blockIdx.y * 64, bn = blockIdx.x * 64;
    const int wm = (w >> 1) * 32, wn = (w & 1) * 32;

    f32x4 acc[2][2];
    #pragma unroll
    for (int i = 0; i < 2; ++i)
        #pragma unroll
        for (int j = 0; j < 2; ++j)
            acc[i][j] = (f32x4){0.f, 0.f, 0.f, 0.f};

    const int ar = tid >> 2, akc = (tid & 3) * 8;   // A stage: row, k-chunk
    const int bkk = tid & 31, bnc = (tid >> 5) * 8; // B stage: k (lane-major), n-chunk

    for (int k0 = 0; k0 < K; k0 += 32) {
        __syncthreads();
        *reinterpret_cast<bf16x8*>(&As[ar][akc]) =
            load8_bf16(&A[(size_t)(bm + ar) * K + k0 + akc]);
        bf16x8 bv = load8_bf16(&B[(size_t)(k0 + bkk) * N + bn + bnc]);
        #pragma unroll
        for (int j = 0; j < 8; ++j) Bs[bnc + j][bkk] = bv[j];
        __syncthreads();

        bf16x8 af0 = *reinterpret_cast<const bf16x8*>(&As[wm + l16][quad * 8]);
        bf16x8 af1 = *reinterpret_cast<const bf16x8*>(&As[wm + 16 + l16][quad * 8]);
        bf16x8 bf0 = *reinterpret_cast<const bf16x8*>(&Bs[wn + l16][quad * 8]);
        bf16x8 bf1 = *reinterpret_cast<const bf16x8*>(&Bs[wn + 16 + l16][quad * 8]);
        acc[0][0] = __builtin_amdgcn_mfma_f32_16x16x32_bf16(af0, bf0, acc[0][0], 0, 0, 0);
        acc[0][1] = __builtin_amdgcn_mfma_f32_16x16x32_bf16(af0, bf1, acc[0][1], 0, 0, 0);
        acc[1][0] = __builtin_amdgcn_mfma_f32_16x16x32_bf16(af1, bf0, acc[1][0], 0, 0, 0);
        acc[1][1] = __builtin_amdgcn_mfma_f32_16x16x32_bf16(af1, bf1, acc[1][1], 0, 0, 0);
    }

    #pragma unroll
    for (int mi = 0; mi < 2; ++mi)
        #pragma unroll
        for (int ni = 0; ni < 2; ++ni)
            #pragma unroll
            for (int r = 0; r < 4; ++r)
                C[(size_t)(bm + wm + 16 * mi + quad * 4 + r) * N + bn + wn + 16 * ni + l16] =
                    (TC)acc[mi][ni][r];
}

// ---------------------------------------------------------------------------
// Split-bf16 GEMM (fp32-grade): acc += Ah*Bh + Ah*Bl + Al*Bh. C fp32.
// Same k-major B staging remap as gemm_nn.
// ---------------------------------------------------------------------------
__global__ __launch_bounds__(256) void gemm_nn_split(const float* __restrict__ A,
                                                     const float* __restrict__ B,
                                                     float* __restrict__ C,
                                                     int M, int N, int K) {
    __shared__ __align__(16) __bf16 Ah[64][32], Al[64][32];
    __shared__ __align__(16) __bf16 Bh[64][32], Bl[64][32];
    const int tid = threadIdx.x;
    const int lane = tid & 63, w = tid >> 6;
    const int quad = lane >> 4, l16 = lane & 15;
    const int bm = blockIdx.y * 64, bn = blockIdx.x * 64;
    const int wm = (w >> 1) * 32, wn = (w & 1) * 32;

    f32x4 acc[2][2];
    #pragma unroll
    for (int i = 0; i < 2; ++i)
        #pragma unroll
        for (int j = 0; j < 2; ++j)
            acc[i][j] = (f32x4){0.f, 0.f, 0.f, 0.f};

    const int ar = tid >> 2, akc = (tid & 3) * 8;
    const int bkk = tid & 31, bnc = (tid >> 5) * 8;

    for (int k0 = 0; k0 < K; k0 += 32) {
        __syncthreads();
        bf16x8 h, l;
        split8(&A[(size_t)(bm + ar) * K + k0 + akc], h, l);
        *reinterpret_cast<bf16x8*>(&Ah[ar][akc]) = h;
        *reinterpret_cast<bf16x8*>(&Al[ar][akc]) = l;
        split8(&B[(size_t)(k0 + bkk) * N + bn + bnc], h, l);
        #pragma unroll
        for (int j = 0; j < 8; ++j) { Bh[bnc + j][bkk] = h[j]; Bl[bnc + j][bkk] = l[j]; }
        __syncthreads();

        bf16x8 ah[2], al[2], bh[2], bl[2];
        #pragma unroll
        for (int i = 0; i < 2; ++i) {
            ah[i] = *reinterpret_cast<const bf16x8*>(&Ah[wm + 16 * i + l16][quad * 8]);
            al[i] = *reinterpret_cast<const bf16x8*>(&Al[wm + 16 * i + l16][quad * 8]);
            bh[i] = *reinterpret_cast<const bf16x8*>(&Bh[wn + 16 * i + l16][quad * 8]);
            bl[i] = *reinterpret_cast<const bf16x8*>(&Bl[wn + 16 * i + l16][quad * 8]);
        }
        #pragma unroll
        for (int mi = 0; mi < 2; ++mi)
            #pragma unroll
            for (int ni = 0; ni < 2; ++ni) {
                acc[mi][ni] = __builtin_amdgcn_mfma_f32_16x16x32_bf16(ah[mi], bh[ni], acc[mi][ni], 0, 0, 0);
                acc[mi][ni] = __builtin_amdgcn_mfma_f32_16x16x32_bf16(ah[mi], bl[ni], acc[mi][ni], 0, 0, 0);
                acc[mi][ni] = __builtin_amdgcn_mfma_f32_16x16x32_bf16(al[mi], bh[ni], acc[mi][ni], 0, 0, 0);
            }
    }

    #pragma unroll
    for (int mi = 0; mi < 2; ++mi)
        #pragma unroll
        for (int ni = 0; ni < 2; ++ni)
            #pragma unroll
            for (int r = 0; r < 4; ++r)
                C[(size_t)(bm + wm + 16 * mi + quad * 4 + r) * N + bn + wn + 16 * ni + l16] =
                    acc[mi][ni][r];
}

// ---------------------------------------------------------------------------
// RoPE in-place on fp32 x:(B,L,N,HD). half=64. ts = 10000^(h/64).
// ---------------------------------------------------------------------------
__global__ __launch_bounds__(256) void rope_kernel(float* __restrict__ x,
                                                   const int* __restrict__ pos,
                                                   int N) {
    size_t idx = (size_t)blockIdx.x * 256 + threadIdx.x;
    int h = (int)(idx & 63);
    size_t g = idx >> 6;            // (b*L + l)*N + n
    size_t bl = g / (size_t)N;      // b*L + l
    float p = (float)pos[bl];
    float ts = powf(10000.f, (float)h * (1.f / 64.f));
    float ang = p / ts;
    float s = sinf(ang), c = cosf(ang);
    size_t base = g * HD;
    float x1 = x[base + h];
    float x2 = x[base + h + 64];
    x[base + h]      = x1 * c - x2 * s;
    x[base + h + 64] = x2 * c + x1 * s;
}

// ---------------------------------------------------------------------------
// Flash attention (non-causal, scale=1.0, GQA group=4), split-precision QK^T.
// Q,K fp32 (RoPE applied); V bf16; O bf16.
// Round-5 changes:
//  - Ksh/Ksl stride 128 -> 136 (68 words mod 32 = 4: kills the 2x read conflict)
//  - V transpose staging remapped s-lane-major: writes are 64 consecutive bf16
//    per wave -> conflict-free (was 16-way, 6.4e7 conflicts/dispatch)
//  - Ps round-trip uses wave-level scheduling fences, not __syncthreads
//    (Ps[w] slices are per-wave; LDS ops complete in-order within a wave)
// LDS: Ksh/Ksl 34.8K + Vt 18.4K + Ps 4K = 57.3 KB -> 2 blocks/CU.
// ---------------------------------------------------------------------------
__global__ __launch_bounds__(256) void attn_kernel(const float* __restrict__ Q,
                                                   const float* __restrict__ K,
                                                   const __bf16* __restrict__ V,
                                                   __bf16* __restrict__ O) {
    __shared__ __align__(16) __bf16 Ksh[64][136], Ksl[64][136];
    __shared__ __align__(16) __bf16 Vt[128][72];
    __shared__ __align__(16) __bf16 Ps[4][16][32];
    const int tid = threadIdx.x, lane = tid & 63, w = tid >> 6;
    const int quad = lane >> 4, l16 = lane & 15;
    const int blk = blockIdx.x;
    const int t0 = (blk & 15) * 64;       // T/64 = 16 q-tiles
    const int n  = (blk >> 4) & 15;       // q head
    const int b  = blk >> 8;              // batch
    const int kn = n >> 2;                // kv head (G=4)

    // Q fragments for this wave's 16 rows, split hi/lo, in registers.
    bf16x8 qh[4], ql[4];
    #pragma unroll
    for (int kh = 0; kh < 4; ++kh) {
        const float* qp = &Q[(((size_t)b * T_SZ + t0 + w * 16 + l16) * NQ + n) * HD + kh * 32 + quad * 8];
        split8(qp, qh[kh], ql[kh]);
    }

    f32x4 o_acc[8];
    #pragma unroll
    for (int i = 0; i < 8; ++i) o_acc[i] = (f32x4){0.f, 0.f, 0.f, 0.f};
    float m_row[4] = {-1e30f, -1e30f, -1e30f, -1e30f};
    float l_row[4] = {0.f, 0.f, 0.f, 0.f};

    for (int s0 = 0; s0 < S_SZ; s0 += 64) {
        __syncthreads();
        #pragma unroll
        for (int i = 0; i < 4; ++i) {
            int e = tid + i * 256;
            // K: row-major staging, vector b128 writes (conflict-free)
            int r = e >> 4, c = (e & 15) * 8;
            bf16x8 h, l;
            split8(&K[(((size_t)b * S_SZ + s0 + r) * NKV + kn) * HD + c], h, l);
            *reinterpret_cast<bf16x8*>(&Ksh[r][c]) = h;
            *reinterpret_cast<bf16x8*>(&Ksl[r][c]) = l;
            // V: transpose staging, s-lane-major (conflict-free writes)
            int vs = e & 63, vc = (e >> 6) * 8;
            bf16x8 vv = *reinterpret_cast<const bf16x8*>(
                &V[(((size_t)b * S_SZ + s0 + vs) * NKV + kn) * HD + vc]);
            #pragma unroll
            for (int j = 0; j < 8; ++j) Vt[vc + j][vs] = vv[j];
        }
        __syncthreads();

        #pragma unroll
        for (int sc = 0; sc < 2; ++sc) {
            // ---- scores: split QK^T (hi*hi + hi*lo + lo*hi) ----
            f32x4 sf[2];
            #pragma unroll
            for (int j2 = 0; j2 < 2; ++j2) {
                f32x4 sa = (f32x4){0.f, 0.f, 0.f, 0.f};
                #pragma unroll
                for (int kh = 0; kh < 4; ++kh) {
                    const int kr = sc * 32 + j2 * 16 + l16, kc = kh * 32 + quad * 8;
                    bf16x8 bkh = *reinterpret_cast<const bf16x8*>(&Ksh[kr][kc]);
                    bf16x8 bkl = *reinterpret_cast<const bf16x8*>(&Ksl[kr][kc]);
                    sa = __builtin_amdgcn_mfma_f32_16x16x32_bf16(qh[kh], bkh, sa, 0, 0, 0);
                    sa = __builtin_amdgcn_mfma_f32_16x16x32_bf16(qh[kh], bkl, sa, 0, 0, 0);
                    sa = __builtin_amdgcn_mfma_f32_16x16x32_bf16(ql[kh], bkh, sa, 0, 0, 0);
                }
                sf[j2] = sa;
            }
            // ---- online softmax (row = quad*4+r, reduce across 16 lanes) ----
            float alpha[4];
            #pragma unroll
            for (int r = 0; r < 4; ++r) {
                float mc = fmaxf(sf[0][r], sf[1][r]);
                #pragma unroll
                for (int off = 1; off < 16; off <<= 1)
                    mc = fmaxf(mc, __shfl_xor(mc, off, 64));
                float mn = fmaxf(m_row[r], mc);
                alpha[r] = fminf(expf(m_row[r] - mn), 1.f);
                m_row[r] = mn;
                float p0 = fminf(expf(sf[0][r] - mn), 1.f);
                float p1 = fminf(expf(sf[1][r] - mn), 1.f);
                sf[0][r] = p0; sf[1][r] = p1;
                float rs = p0 + p1;
                #pragma unroll
                for (int off = 1; off < 16; off <<= 1)
                    rs += __shfl_xor(rs, off, 64);
                l_row[r] = l_row[r] * alpha[r] + rs;
            }
            #pragma unroll
            for (int ht = 0; ht < 8; ++ht)
                #pragma unroll
                for (int r = 0; r < 4; ++r)
                    o_acc[ht][r] *= alpha[r];
            // ---- P: C-layout -> A-layout via per-wave LDS slice ----
            // Ps[w] is private to wave w; DS ops complete in-order within a
            // wave, so only compiler scheduling fences are needed.
            #pragma unroll
            for (int r = 0; r < 4; ++r) {
                Ps[w][quad * 4 + r][l16]      = (__bf16)sf[0][r];
                Ps[w][quad * 4 + r][16 + l16] = (__bf16)sf[1][r];
            }
            __builtin_amdgcn_wave_barrier();
            bf16x8 ap = *reinterpret_cast<const bf16x8*>(&Ps[w][l16][quad * 8]);
            __builtin_amdgcn_wave_barrier();
            // ---- O += P @ V ----
            #pragma unroll
            for (int ht = 0; ht < 8; ++ht) {
                bf16x8 bv = *reinterpret_cast<const bf16x8*>(&Vt[ht * 16 + l16][sc * 32 + quad * 8]);
                o_acc[ht] = __builtin_amdgcn_mfma_f32_16x16x32_bf16(ap, bv, o_acc[ht], 0, 0, 0);
            }
        }
    }

    float inv_l[4];
    #pragma unroll
    for (int r = 0; r < 4; ++r) inv_l[r] = 1.f / fmaxf(l_row[r], 1e-30f);
    #pragma unroll
    for (int ht = 0; ht < 8; ++ht)
        #pragma unroll
        for (int r = 0; r < 4; ++r)
            O[(((size_t)b * T_SZ + t0 + w * 16 + quad * 4 + r) * NQ + n) * HD + ht * 16 + l16] =
                (__bf16)(o_acc[ht][r] * inv_l[r]);
}

// ---------------------------------------------------------------------------
extern "C" void kernel_launch(void* const* d_in, const int* in_sizes, int n_in,
                              void* d_out, int out_size, void* d_ws, size_t ws_size,
                              hipStream_t stream) {
    const float* Xq   = (const float*)d_in[0];   // (B,T,DQ)
    const float* Xkv  = (const float*)d_in[1];   // (B,S,DKV)
    const int*   qpos = (const int*)d_in[2];     // (B,T)
    const int*   kpos = (const int*)d_in[3];     // (B,S)
    const float* Wq   = (const float*)d_in[4];   // (DQ, NQ*HD)
    const float* Wk   = (const float*)d_in[5];   // (DKV, NKV*HD)
    const float* Wv   = (const float*)d_in[6];   // (DKV, NKV*HD)
    const float* Wo   = (const float*)d_in[7];   // (NQ*HD, DOUT)
    float* out = (float*)d_out;                  // (B,T,DOUT) fp32

    // workspace: Qf 16.8MB fp32 | Kf 4.2MB fp32 | Vb 2.1MB bf16 | Ab 8.4MB bf16
    float* Qf = (float*)d_ws;
    float* Kf = Qf + (size_t)B_SZ * T_SZ * NQ * HD;
    __bf16* Vb = (__bf16*)(Kf + (size_t)B_SZ * S_SZ * NKV * HD);
    __bf16* Ab = Vb + (size_t)B_SZ * S_SZ * NKV * HD;

    dim3 blk(256);
    // Q,K projections: split-precision (score path) -> fp32 workspace
    gemm_nn_split<<<dim3((NQ * HD) / 64, (B_SZ * T_SZ) / 64), blk, 0, stream>>>(
        Xq, Wq, Qf, B_SZ * T_SZ, NQ * HD, DQ);
    gemm_nn_split<<<dim3((NKV * HD) / 64, (B_SZ * S_SZ) / 64), blk, 0, stream>>>(
        Xkv, Wk, Kf, B_SZ * S_SZ, NKV * HD, DKV);
    // V projection: plain bf16 path
    gemm_nn<float, float, __bf16><<<dim3((NKV * HD) / 64, (B_SZ * S_SZ) / 64), blk, 0, stream>>>(
        Xkv, Wv, Vb, B_SZ * S_SZ, NKV * HD, DKV);
    // RoPE on q and k (fp32)
    rope_kernel<<<(B_SZ * T_SZ * NQ * 64) / 256, blk, 0, stream>>>(Qf, qpos, NQ);
    rope_kernel<<<(B_SZ * S_SZ * NKV * 64) / 256, blk, 0, stream>>>(Kf, kpos, NKV);
    // GQA flash attention (split QK^T) -> attn bf16 (B,T,NQ,HD)
    attn_kernel<<<B_SZ * NQ * (T_SZ / 64), blk, 0, stream>>>(Qf, Kf, Vb, Ab);
    // output projection: bf16 attn x fp32 Wo -> fp32 out
    gemm_nn<__bf16, float, float><<<dim3(DOUT / 64, (B_SZ * T_SZ) / 64), blk, 0, stream>>>(
        Ab, Wo, out, B_SZ * T_SZ, DOUT, NQ * HD);
}